// Round 21
// baseline (139.497 us; speedup 1.0000x reference)
//
#include <hip/hip_runtime.h>

#define N_NODES 100000
#define N_EDGES 1600000
#define IN_F 512
#define OUT_F 64

#define NBINS 391          // coarse buckets: dst >> 8  (99999>>8 = 390)
#define K3_CHUNK 4096      // edges per scatter block
#define K3_BLOCKS ((N_EDGES + K3_CHUNK - 1) / K3_CHUNK)   // 391
#define GEMM_BLOCKS ((N_NODES + 255) / 256)               // 391 (256 rows/block, 8 waves x 32 rows)
#define CAP 6144           // slots per bucket (mean 4096, +32 sigma)

typedef __bf16 bf16_t;
typedef bf16_t bf16x8 __attribute__((ext_vector_type(8)));
typedef float f32x4 __attribute__((ext_vector_type(4)));

__device__ __forceinline__ unsigned short f2bf(float f) {
    unsigned int u = __float_as_uint(f);
    u += 0x7FFFu + ((u >> 16) & 1u);        // round-to-nearest-even
    return (unsigned short)(u >> 16);
}
__device__ __forceinline__ float bf2f(unsigned short s) {
    return __uint_as_float((unsigned int)s << 16);
}

// ---------------- prep: Wt[n][k] = bf16(W[k][n]); also inits gcursor ----------------
__global__ __launch_bounds__(256) void prep_wt(const float* __restrict__ W,
                                               unsigned short* __restrict__ Wt,
                                               int* __restrict__ gcursor) {
    const int i = blockIdx.x * 256 + threadIdx.x;   // 0..32767
    const int k = i >> 6, n = i & 63;
    Wt[(size_t)n * IN_F + k] = f2bf(W[i]);
    if (i < 512) gcursor[i] = i * CAP;              // covers NBINS=391
}

// ---------------- fused: coarse scatter (blocks 0..390) + MFMA GEMM (blocks 391..781) ----------------
// Round-14 configuration (session best, 139.0 us): contiguous role split,
// 2-rf GEMM (48 VGPR, no spills), K3_CHUNK=4096.
// meta word0 = src | (dst & 255) << 17
__global__ __launch_bounds__(512) void scatter_gemm(const int* __restrict__ esrc,
                                                    const int* __restrict__ edst,
                                                    const float* __restrict__ ew,
                                                    int* __restrict__ gcursor,
                                                    int2* __restrict__ meta,
                                                    const float* __restrict__ A,
                                                    const unsigned short* __restrict__ Wt,
                                                    unsigned short* __restrict__ H) {
    __shared__ int hist[NBINS];
    __shared__ int base[NBINS];
    __shared__ int binstart[NBINS];
    __shared__ int lcur[NBINS];
    __shared__ int wsum[8];
    __shared__ int2 sorted[K3_CHUNK];              // 32 KB
    __shared__ unsigned short binof[K3_CHUNK];     // 8 KB

    const int t = threadIdx.x;
    const int wv = t >> 6, ln = t & 63;

    if (blockIdx.x >= K3_BLOCKS) {
        // ================= GEMM role: 8 waves x 32 rows = 256 rows =================
        const int gb = blockIdx.x - K3_BLOCKS;
        const int arow = ln & 15;
        const int kk = (ln >> 4) << 3;   // 0,8,16,24

        const float* ap[2];
        #pragma unroll
        for (int rf = 0; rf < 2; ++rf) {
            int r = gb * 256 + (wv << 5) + (rf << 4) + arow;
            if (r >= N_NODES) r = N_NODES - 1;          // clamp tail (writes guarded)
            ap[rf] = A + (size_t)r * IN_F + kk;
        }

        f32x4 acc[2][4];
        #pragma unroll
        for (int i = 0; i < 2; ++i)
            #pragma unroll
            for (int j = 0; j < 4; ++j)
                acc[i][j] = (f32x4){0.f, 0.f, 0.f, 0.f};

        float4 nxt[2][2];
        #pragma unroll
        for (int rf = 0; rf < 2; ++rf) {
            nxt[rf][0] = *(const float4*)(ap[rf] + 0);
            nxt[rf][1] = *(const float4*)(ap[rf] + 4);
        }

        for (int k0 = 0; k0 < IN_F; k0 += 32) {
            float4 cur[2][2];
            #pragma unroll
            for (int rf = 0; rf < 2; ++rf) {
                cur[rf][0] = nxt[rf][0];
                cur[rf][1] = nxt[rf][1];
            }
            if (k0 + 32 < IN_F) {
                #pragma unroll
                for (int rf = 0; rf < 2; ++rf) {
                    nxt[rf][0] = *(const float4*)(ap[rf] + k0 + 32);
                    nxt[rf][1] = *(const float4*)(ap[rf] + k0 + 36);
                }
            }

            bf16x8 afrag[2];
            #pragma unroll
            for (int rf = 0; rf < 2; ++rf) {
                bf16x8 af;
                af[0] = (bf16_t)cur[rf][0].x; af[1] = (bf16_t)cur[rf][0].y;
                af[2] = (bf16_t)cur[rf][0].z; af[3] = (bf16_t)cur[rf][0].w;
                af[4] = (bf16_t)cur[rf][1].x; af[5] = (bf16_t)cur[rf][1].y;
                af[6] = (bf16_t)cur[rf][1].z; af[7] = (bf16_t)cur[rf][1].w;
                afrag[rf] = af;
            }

            bf16x8 bfrag[4];
            #pragma unroll
            for (int cf = 0; cf < 4; ++cf) {
                const int col = (cf << 4) + arow;
                bfrag[cf] = *(const bf16x8*)(Wt + (size_t)col * IN_F + k0 + kk);
            }

            #pragma unroll
            for (int rf = 0; rf < 2; ++rf)
                #pragma unroll
                for (int cf = 0; cf < 4; ++cf)
                    acc[rf][cf] = __builtin_amdgcn_mfma_f32_16x16x32_bf16(
                        afrag[rf], bfrag[cf], acc[rf][cf], 0, 0, 0);
        }

        #pragma unroll
        for (int rf = 0; rf < 2; ++rf) {
            const int rbase = gb * 256 + (wv << 5) + (rf << 4) + ((ln >> 4) << 2);
            #pragma unroll
            for (int j = 0; j < 4; ++j) {
                const int row = rbase + j;
                if (row < N_NODES) {
                    #pragma unroll
                    for (int cf = 0; cf < 4; ++cf) {
                        const int col = (cf << 4) + arow;
                        H[(size_t)row * OUT_F + col] = f2bf(acc[rf][cf][j]);
                    }
                }
            }
        }
        return;
    }

    // ================= scatter role =================
    const int e0 = blockIdx.x * K3_CHUNK;

    for (int i = t; i < NBINS; i += 512) { hist[i] = 0; lcur[i] = 0; }
    __syncthreads();

    int2 ed[8];
    int  bins[8];
    #pragma unroll
    for (int i = 0; i < 8; ++i) {
        const int e = e0 + i * 512 + t;
        if (e < N_EDGES) {
            const int s = esrc[e];
            const int d = edst[e];
            bins[i] = d >> 8;
            ed[i] = make_int2(s | ((d & 255) << 17), __float_as_int(ew[e]));
            atomicAdd(&hist[bins[i]], 1);
        } else {
            bins[i] = -1;
        }
    }
    __syncthreads();

    // wave-level inclusive scan over 512 slots (2 barriers total)
    const int v = (t < NBINS) ? hist[t] : 0;
    int x = v;
    #pragma unroll
    for (int off = 1; off < 64; off <<= 1) {
        const int y = __shfl_up(x, off, 64);
        if (ln >= off) x += y;
    }
    if (ln == 63) wsum[wv] = x;
    __syncthreads();
    int pre = 0, tot = 0;
    #pragma unroll
    for (int k = 0; k < 8; ++k) {
        const int s = wsum[k];
        if (k < wv) pre += s;
        tot += s;
    }
    x += pre;
    if (t < NBINS) {
        binstart[t] = x - v;
        base[t] = (v > 0) ? atomicAdd(&gcursor[t], v) : 0;
    }
    __syncthreads();

    #pragma unroll
    for (int i = 0; i < 8; ++i) {
        if (bins[i] >= 0) {
            const int r = atomicAdd(&lcur[bins[i]], 1);
            const int slot = binstart[bins[i]] + r;
            sorted[slot] = ed[i];
            binof[slot] = (unsigned short)bins[i];
        }
    }
    __syncthreads();

    for (int s = t; s < tot; s += 512) {
        const int b = binof[s];
        meta[base[b] + (s - binstart[b])] = sorted[s];
    }
}

// ---------------- K4: per-bucket fine sort -> packed 4B meta2 + start/counts ----------------
// meta2 entry = src(17b) | bf16_w_no_sign(15b) << 17
__global__ __launch_bounds__(512) void fine_sort(const int2* __restrict__ meta,
                                                 const int* __restrict__ gcursor,
                                                 unsigned int* __restrict__ meta2,
                                                 int* __restrict__ start,
                                                 int* __restrict__ counts) {
    __shared__ int hist[256];
    __shared__ int scn[256];
    __shared__ int cur[256];
    __shared__ int ws4[4];
    __shared__ unsigned int sorted[CAP];    // 24 KB

    const int b = blockIdx.x;
    const int t = threadIdx.x;
    const int wv = t >> 6, ln = t & 63;
    const size_t s0 = (size_t)b * CAP;
    int cnt = gcursor[b] - b * CAP;
    if (cnt > CAP) cnt = CAP;       // unreachable (+32 sigma margin)

    if (t < 256) { hist[t] = 0; cur[t] = 0; }
    __syncthreads();

    for (int i = t; i < cnt; i += 512)
        atomicAdd(&hist[(meta[s0 + i].x >> 17) & 255], 1);
    __syncthreads();

    const int v = (t < 256) ? hist[t] : 0;
    int x = v;
    #pragma unroll
    for (int off = 1; off < 64; off <<= 1) {
        const int y = __shfl_up(x, off, 64);
        if (ln >= off) x += y;
    }
    if (t < 256 && ln == 63) ws4[wv] = x;
    __syncthreads();
    if (t < 256) {
        int pre = 0;
        #pragma unroll
        for (int k = 0; k < 4; ++k) if (k < wv) pre += ws4[k];
        scn[t] = x + pre;
    }
    __syncthreads();

    for (int i = t; i < cnt; i += 512) {
        const int2 m = meta[s0 + i];
        const int ld = (m.x >> 17) & 255;
        const unsigned int wb = f2bf(__int_as_float(m.y));   // sign bit 0 (w >= 0)
        const unsigned int p = (unsigned int)(m.x & 0x1FFFF) | (wb << 17);
        const int r = atomicAdd(&cur[ld], 1);
        sorted[(scn[ld] - hist[ld]) + r] = p;
    }
    __syncthreads();

    for (int i = t; i < cnt; i += 512) meta2[s0 + i] = sorted[i];
    const int node0 = b << 8;
    if (t < 256 && node0 + t < N_NODES) {
        counts[node0 + t] = hist[t];
        start[node0 + t]  = (int)s0 + scn[t] - hist[t];
    }
}

// ---------------- aggregation: FOUR nodes per wave (4x gather ILP), lane = feature ----------------
__global__ __launch_bounds__(256) void aggregate_kernel(const unsigned short* __restrict__ h,
                                                        const int* __restrict__ start,
                                                        const int* __restrict__ counts,
                                                        const unsigned int* __restrict__ meta,
                                                        const float* __restrict__ bias,
                                                        float* __restrict__ out) {
    const int wave = threadIdx.x >> 6;
    const int lane = threadIdx.x & 63;
    const int n0 = blockIdx.x * 16 + wave * 4;     // 6250 blocks x 16 nodes = 100000 exactly
    const int g = lane & 15;

    int s[4], c[4];
    #pragma unroll
    for (int q = 0; q < 4; ++q) { s[q] = start[n0 + q]; c[q] = counts[n0 + q]; }

    float acc[4] = {0.f, 0.f, 0.f, 0.f};
    int maxc = c[0];
    #pragma unroll
    for (int q = 1; q < 4; ++q) maxc = max(maxc, c[q]);

    for (int b = 0; b < maxc; b += 16) {
        // masked loads; dummies are 0 -> (src=0, w=+0.0f) -> contribute exactly 0
        unsigned int m[4];
        #pragma unroll
        for (int q = 0; q < 4; ++q)
            m[q] = (g < c[q] - b) ? meta[(size_t)s[q] + b + g] : 0u;
        #pragma unroll
        for (int j = 0; j < 16; ++j) {
            #pragma unroll
            for (int q = 0; q < 4; ++q) {
                const unsigned int p = __shfl(m[q], j, 16);
                const int   src = (int)(p & 0x1FFFF);
                const float wv  = __uint_as_float((p >> 17) << 16);
                acc[q] = fmaf(bf2f(h[(size_t)src * OUT_F + lane]), wv, acc[q]);
            }
        }
    }

    const float bv = bias[lane];
    #pragma unroll
    for (int q = 0; q < 4; ++q) {
        const float r = (c[q] > 0) ? (acc[q] / (float)c[q]) : 0.f;
        out[(size_t)(n0 + q) * OUT_F + lane] = fmaxf(r + bv, 0.f);
    }
}

extern "C" void kernel_launch(void* const* d_in, const int* in_sizes, int n_in,
                              void* d_out, int out_size, void* d_ws, size_t ws_size,
                              hipStream_t stream) {
    const float* feat   = (const float*)d_in[0];
    const float* edge_w = (const float*)d_in[1];
    const float* weight = (const float*)d_in[2];
    const float* bias   = (const float*)d_in[3];
    const int*   esrc   = (const int*)d_in[4];
    const int*   edst   = (const int*)d_in[5];

    float* out = (float*)d_out;

    // workspace layout (8B-aligned)
    char* ws = (char*)d_ws;
    int2*           meta  = (int2*)ws;            ws += (size_t)NBINS * CAP * 8;       // 19.2 MB
    unsigned int*   meta2 = (unsigned int*)ws;    ws += (size_t)NBINS * CAP * 4;       // 9.6 MB
    unsigned short* h     = (unsigned short*)ws;  ws += (size_t)N_NODES * OUT_F * 2;   // 12.8 MB
    unsigned short* Wt    = (unsigned short*)ws;  ws += (size_t)OUT_F * IN_F * 2;      // 64 KB
    int* counts  = (int*)ws;  ws += (size_t)N_NODES * 4;
    int* start   = (int*)ws;  ws += (size_t)N_NODES * 4;
    int* gcursor = (int*)ws;  ws += 512 * 4;

    prep_wt<<<(IN_F * OUT_F) / 256, 256, 0, stream>>>(weight, Wt, gcursor);
    scatter_gemm<<<K3_BLOCKS + GEMM_BLOCKS, 512, 0, stream>>>(esrc, edst, edge_w,
                                                              gcursor, meta,
                                                              feat, Wt, h);
    fine_sort<<<NBINS, 512, 0, stream>>>(meta, gcursor, meta2, start, counts);
    aggregate_kernel<<<N_NODES / 16, 256, 0, stream>>>(h, start, counts,
                                                       meta2, bias, out);
}

// Round 22
// 138.404 us; speedup vs baseline: 1.0079x; 1.0079x over previous
//
#include <hip/hip_runtime.h>

#define N_NODES 100000
#define N_EDGES 1600000
#define IN_F 512
#define OUT_F 64

#define NBINS 391          // coarse buckets: dst >> 8  (99999>>8 = 390)
#define K3_CHUNK 4096      // edges per scatter block
#define K3_BLOCKS ((N_EDGES + K3_CHUNK - 1) / K3_CHUNK)   // 391
#define GEMM_BLOCKS ((N_NODES + 255) / 256)               // 391 (256 rows/block, 8 waves x 32 rows)
#define CAP 6144           // slots per bucket (mean 4096, +32 sigma)

typedef __bf16 bf16_t;
typedef bf16_t bf16x8 __attribute__((ext_vector_type(8)));
typedef float f32x4 __attribute__((ext_vector_type(4)));

__device__ __forceinline__ unsigned short f2bf(float f) {
    unsigned int u = __float_as_uint(f);
    u += 0x7FFFu + ((u >> 16) & 1u);        // round-to-nearest-even
    return (unsigned short)(u >> 16);
}
__device__ __forceinline__ float bf2f(unsigned short s) {
    return __uint_as_float((unsigned int)s << 16);
}

// ---------------- prep: Wt[n][k] = bf16(W[k][n]); also inits gcursor ----------------
__global__ __launch_bounds__(256) void prep_wt(const float* __restrict__ W,
                                               unsigned short* __restrict__ Wt,
                                               int* __restrict__ gcursor) {
    const int i = blockIdx.x * 256 + threadIdx.x;   // 0..32767
    const int k = i >> 6, n = i & 63;
    Wt[(size_t)n * IN_F + k] = f2bf(W[i]);
    if (i < 512) gcursor[i] = i * CAP;              // covers NBINS=391
}

// ---------------- fused: coarse scatter (blocks 0..390) + MFMA GEMM (blocks 391..781) ----------------
// Round-14 configuration (session best, 139.0 us): contiguous role split,
// 2-rf GEMM (48 VGPR, no spills), K3_CHUNK=4096.
// meta word0 = src | (dst & 255) << 17
__global__ __launch_bounds__(512) void scatter_gemm(const int* __restrict__ esrc,
                                                    const int* __restrict__ edst,
                                                    const float* __restrict__ ew,
                                                    int* __restrict__ gcursor,
                                                    int2* __restrict__ meta,
                                                    const float* __restrict__ A,
                                                    const unsigned short* __restrict__ Wt,
                                                    unsigned short* __restrict__ H) {
    __shared__ int hist[NBINS];
    __shared__ int base[NBINS];
    __shared__ int binstart[NBINS];
    __shared__ int lcur[NBINS];
    __shared__ int wsum[8];
    __shared__ int2 sorted[K3_CHUNK];              // 32 KB
    __shared__ unsigned short binof[K3_CHUNK];     // 8 KB

    const int t = threadIdx.x;
    const int wv = t >> 6, ln = t & 63;

    if (blockIdx.x >= K3_BLOCKS) {
        // ================= GEMM role: 8 waves x 32 rows = 256 rows =================
        const int gb = blockIdx.x - K3_BLOCKS;
        const int arow = ln & 15;
        const int kk = (ln >> 4) << 3;   // 0,8,16,24

        const float* ap[2];
        #pragma unroll
        for (int rf = 0; rf < 2; ++rf) {
            int r = gb * 256 + (wv << 5) + (rf << 4) + arow;
            if (r >= N_NODES) r = N_NODES - 1;          // clamp tail (writes guarded)
            ap[rf] = A + (size_t)r * IN_F + kk;
        }

        f32x4 acc[2][4];
        #pragma unroll
        for (int i = 0; i < 2; ++i)
            #pragma unroll
            for (int j = 0; j < 4; ++j)
                acc[i][j] = (f32x4){0.f, 0.f, 0.f, 0.f};

        float4 nxt[2][2];
        #pragma unroll
        for (int rf = 0; rf < 2; ++rf) {
            nxt[rf][0] = *(const float4*)(ap[rf] + 0);
            nxt[rf][1] = *(const float4*)(ap[rf] + 4);
        }

        for (int k0 = 0; k0 < IN_F; k0 += 32) {
            float4 cur[2][2];
            #pragma unroll
            for (int rf = 0; rf < 2; ++rf) {
                cur[rf][0] = nxt[rf][0];
                cur[rf][1] = nxt[rf][1];
            }
            if (k0 + 32 < IN_F) {
                #pragma unroll
                for (int rf = 0; rf < 2; ++rf) {
                    nxt[rf][0] = *(const float4*)(ap[rf] + k0 + 32);
                    nxt[rf][1] = *(const float4*)(ap[rf] + k0 + 36);
                }
            }

            bf16x8 afrag[2];
            #pragma unroll
            for (int rf = 0; rf < 2; ++rf) {
                bf16x8 af;
                af[0] = (bf16_t)cur[rf][0].x; af[1] = (bf16_t)cur[rf][0].y;
                af[2] = (bf16_t)cur[rf][0].z; af[3] = (bf16_t)cur[rf][0].w;
                af[4] = (bf16_t)cur[rf][1].x; af[5] = (bf16_t)cur[rf][1].y;
                af[6] = (bf16_t)cur[rf][1].z; af[7] = (bf16_t)cur[rf][1].w;
                afrag[rf] = af;
            }

            bf16x8 bfrag[4];
            #pragma unroll
            for (int cf = 0; cf < 4; ++cf) {
                const int col = (cf << 4) + arow;
                bfrag[cf] = *(const bf16x8*)(Wt + (size_t)col * IN_F + k0 + kk);
            }

            #pragma unroll
            for (int rf = 0; rf < 2; ++rf)
                #pragma unroll
                for (int cf = 0; cf < 4; ++cf)
                    acc[rf][cf] = __builtin_amdgcn_mfma_f32_16x16x32_bf16(
                        afrag[rf], bfrag[cf], acc[rf][cf], 0, 0, 0);
        }

        #pragma unroll
        for (int rf = 0; rf < 2; ++rf) {
            const int rbase = gb * 256 + (wv << 5) + (rf << 4) + ((ln >> 4) << 2);
            #pragma unroll
            for (int j = 0; j < 4; ++j) {
                const int row = rbase + j;
                if (row < N_NODES) {
                    #pragma unroll
                    for (int cf = 0; cf < 4; ++cf) {
                        const int col = (cf << 4) + arow;
                        H[(size_t)row * OUT_F + col] = f2bf(acc[rf][cf][j]);
                    }
                }
            }
        }
        return;
    }

    // ================= scatter role =================
    const int e0 = blockIdx.x * K3_CHUNK;

    for (int i = t; i < NBINS; i += 512) { hist[i] = 0; lcur[i] = 0; }
    __syncthreads();

    int2 ed[8];
    int  bins[8];
    #pragma unroll
    for (int i = 0; i < 8; ++i) {
        const int e = e0 + i * 512 + t;
        if (e < N_EDGES) {
            const int s = esrc[e];
            const int d = edst[e];
            bins[i] = d >> 8;
            ed[i] = make_int2(s | ((d & 255) << 17), __float_as_int(ew[e]));
            atomicAdd(&hist[bins[i]], 1);
        } else {
            bins[i] = -1;
        }
    }
    __syncthreads();

    // wave-level inclusive scan over 512 slots (2 barriers total)
    const int v = (t < NBINS) ? hist[t] : 0;
    int x = v;
    #pragma unroll
    for (int off = 1; off < 64; off <<= 1) {
        const int y = __shfl_up(x, off, 64);
        if (ln >= off) x += y;
    }
    if (ln == 63) wsum[wv] = x;
    __syncthreads();
    int pre = 0, tot = 0;
    #pragma unroll
    for (int k = 0; k < 8; ++k) {
        const int s = wsum[k];
        if (k < wv) pre += s;
        tot += s;
    }
    x += pre;
    if (t < NBINS) {
        binstart[t] = x - v;
        base[t] = (v > 0) ? atomicAdd(&gcursor[t], v) : 0;
    }
    __syncthreads();

    #pragma unroll
    for (int i = 0; i < 8; ++i) {
        if (bins[i] >= 0) {
            const int r = atomicAdd(&lcur[bins[i]], 1);
            const int slot = binstart[bins[i]] + r;
            sorted[slot] = ed[i];
            binof[slot] = (unsigned short)bins[i];
        }
    }
    __syncthreads();

    for (int s = t; s < tot; s += 512) {
        const int b = binof[s];
        meta[base[b] + (s - binstart[b])] = sorted[s];
    }
}

// ---------------- K4: per-bucket fine sort -> packed 4B meta2 + start/counts ----------------
// meta2 entry = src(17b) | bf16_w_no_sign(15b) << 17
__global__ __launch_bounds__(512) void fine_sort(const int2* __restrict__ meta,
                                                 const int* __restrict__ gcursor,
                                                 unsigned int* __restrict__ meta2,
                                                 int* __restrict__ start,
                                                 int* __restrict__ counts) {
    __shared__ int hist[256];
    __shared__ int scn[256];
    __shared__ int cur[256];
    __shared__ int ws4[4];
    __shared__ unsigned int sorted[CAP];    // 24 KB

    const int b = blockIdx.x;
    const int t = threadIdx.x;
    const int wv = t >> 6, ln = t & 63;
    const size_t s0 = (size_t)b * CAP;
    int cnt = gcursor[b] - b * CAP;
    if (cnt > CAP) cnt = CAP;       // unreachable (+32 sigma margin)

    if (t < 256) { hist[t] = 0; cur[t] = 0; }
    __syncthreads();

    for (int i = t; i < cnt; i += 512)
        atomicAdd(&hist[(meta[s0 + i].x >> 17) & 255], 1);
    __syncthreads();

    const int v = (t < 256) ? hist[t] : 0;
    int x = v;
    #pragma unroll
    for (int off = 1; off < 64; off <<= 1) {
        const int y = __shfl_up(x, off, 64);
        if (ln >= off) x += y;
    }
    if (t < 256 && ln == 63) ws4[wv] = x;
    __syncthreads();
    if (t < 256) {
        int pre = 0;
        #pragma unroll
        for (int k = 0; k < 4; ++k) if (k < wv) pre += ws4[k];
        scn[t] = x + pre;
    }
    __syncthreads();

    for (int i = t; i < cnt; i += 512) {
        const int2 m = meta[s0 + i];
        const int ld = (m.x >> 17) & 255;
        const unsigned int wb = f2bf(__int_as_float(m.y));   // sign bit 0 (w >= 0)
        const unsigned int p = (unsigned int)(m.x & 0x1FFFF) | (wb << 17);
        const int r = atomicAdd(&cur[ld], 1);
        sorted[(scn[ld] - hist[ld]) + r] = p;
    }
    __syncthreads();

    for (int i = t; i < cnt; i += 512) meta2[s0 + i] = sorted[i];
    const int node0 = b << 8;
    if (t < 256 && node0 + t < N_NODES) {
        counts[node0 + t] = hist[t];
        start[node0 + t]  = (int)s0 + scn[t] - hist[t];
    }
}

// ---------------- aggregation: FOUR nodes per wave (4x gather ILP), lane = feature ----------------
__global__ __launch_bounds__(256) void aggregate_kernel(const unsigned short* __restrict__ h,
                                                        const int* __restrict__ start,
                                                        const int* __restrict__ counts,
                                                        const unsigned int* __restrict__ meta,
                                                        const float* __restrict__ bias,
                                                        float* __restrict__ out) {
    const int wave = threadIdx.x >> 6;
    const int lane = threadIdx.x & 63;
    const int n0 = blockIdx.x * 16 + wave * 4;     // 6250 blocks x 16 nodes = 100000 exactly
    const int g = lane & 15;

    int s[4], c[4];
    #pragma unroll
    for (int q = 0; q < 4; ++q) { s[q] = start[n0 + q]; c[q] = counts[n0 + q]; }

    float acc[4] = {0.f, 0.f, 0.f, 0.f};
    int maxc = c[0];
    #pragma unroll
    for (int q = 1; q < 4; ++q) maxc = max(maxc, c[q]);

    for (int b = 0; b < maxc; b += 16) {
        // masked loads; dummies are 0 -> (src=0, w=+0.0f) -> contribute exactly 0
        unsigned int m[4];
        #pragma unroll
        for (int q = 0; q < 4; ++q)
            m[q] = (g < c[q] - b) ? meta[(size_t)s[q] + b + g] : 0u;
        #pragma unroll
        for (int j = 0; j < 16; ++j) {
            #pragma unroll
            for (int q = 0; q < 4; ++q) {
                const unsigned int p = __shfl(m[q], j, 16);
                const int   src = (int)(p & 0x1FFFF);
                const float wv  = __uint_as_float((p >> 17) << 16);
                acc[q] = fmaf(bf2f(h[(size_t)src * OUT_F + lane]), wv, acc[q]);
            }
        }
    }

    const float bv = bias[lane];
    #pragma unroll
    for (int q = 0; q < 4; ++q) {
        const float r = (c[q] > 0) ? (acc[q] / (float)c[q]) : 0.f;
        out[(size_t)(n0 + q) * OUT_F + lane] = fmaxf(r + bv, 0.f);
    }
}

extern "C" void kernel_launch(void* const* d_in, const int* in_sizes, int n_in,
                              void* d_out, int out_size, void* d_ws, size_t ws_size,
                              hipStream_t stream) {
    const float* feat   = (const float*)d_in[0];
    const float* edge_w = (const float*)d_in[1];
    const float* weight = (const float*)d_in[2];
    const float* bias   = (const float*)d_in[3];
    const int*   esrc   = (const int*)d_in[4];
    const int*   edst   = (const int*)d_in[5];

    float* out = (float*)d_out;

    // workspace layout (8B-aligned)
    char* ws = (char*)d_ws;
    int2*           meta  = (int2*)ws;            ws += (size_t)NBINS * CAP * 8;       // 19.2 MB
    unsigned int*   meta2 = (unsigned int*)ws;    ws += (size_t)NBINS * CAP * 4;       // 9.6 MB
    unsigned short* h     = (unsigned short*)ws;  ws += (size_t)N_NODES * OUT_F * 2;   // 12.8 MB
    unsigned short* Wt    = (unsigned short*)ws;  ws += (size_t)OUT_F * IN_F * 2;      // 64 KB
    int* counts  = (int*)ws;  ws += (size_t)N_NODES * 4;
    int* start   = (int*)ws;  ws += (size_t)N_NODES * 4;
    int* gcursor = (int*)ws;  ws += 512 * 4;

    prep_wt<<<(IN_F * OUT_F) / 256, 256, 0, stream>>>(weight, Wt, gcursor);
    scatter_gemm<<<K3_BLOCKS + GEMM_BLOCKS, 512, 0, stream>>>(esrc, edst, edge_w,
                                                              gcursor, meta,
                                                              feat, Wt, h);
    fine_sort<<<NBINS, 512, 0, stream>>>(meta, gcursor, meta2, start, counts);
    aggregate_kernel<<<N_NODES / 16, 256, 0, stream>>>(h, start, counts,
                                                       meta2, bias, out);
}